// Round 1
// baseline (765.770 us; speedup 1.0000x reference)
//
#include <hip/hip_runtime.h>
#include <math.h>

#define D_MODEL 768
#define HEADS 12
#define DK 64
#define SEQ 2048
#define BATCH 2
#define MTOT (BATCH * SEQ)   // 4096

// ---------------- GEMM: C[M,N] = A[M,K] @ W[K,N] + bias[N] (all fp32) -------
#define GBM 64
#define GBN 64
#define GBK 16

__global__ __launch_bounds__(256) void gemm_bias_k(
    const float* __restrict__ A, const float* __restrict__ W,
    const float* __restrict__ bias, float* __restrict__ C,
    int M, int N, int K)
{
    __shared__ float As[GBK][GBM];   // transposed A tile: As[k][m]
    __shared__ float Bs[GBK][GBN];

    const int tid = threadIdx.x;            // 256 threads
    const int tx = tid & 15;                // 0..15 (N direction)
    const int ty = tid >> 4;                // 0..15 (M direction)
    const int brow = blockIdx.y * GBM;
    const int bcol = blockIdx.x * GBN;

    // A-tile load mapping: 64 rows x 16 k; 4 lanes cover one 64B row.
    const int ar = tid >> 2;                // 0..63
    const int ac = (tid & 3) << 2;          // 0,4,8,12
    // B-tile load mapping: 16 rows x 64 cols; 16 lanes cover one 256B row.
    const int br = tid >> 4;                // 0..15
    const int bc = (tid & 15) << 2;         // 0..60

    float acc[4][4] = {};

    for (int k0 = 0; k0 < K; k0 += GBK) {
        float4 av = *(const float4*)(A + (size_t)(brow + ar) * K + k0 + ac);
        float4 bv = *(const float4*)(W + (size_t)(k0 + br) * N + bcol + bc);
        As[ac + 0][ar] = av.x;
        As[ac + 1][ar] = av.y;
        As[ac + 2][ar] = av.z;
        As[ac + 3][ar] = av.w;
        *(float4*)&Bs[br][bc] = bv;
        __syncthreads();

        #pragma unroll
        for (int kk = 0; kk < GBK; ++kk) {
            float a[4], b[4];
            *(float4*)a = *(const float4*)&As[kk][ty * 4];
            *(float4*)b = *(const float4*)&Bs[kk][tx * 4];
            #pragma unroll
            for (int i = 0; i < 4; ++i)
                #pragma unroll
                for (int j = 0; j < 4; ++j)
                    acc[i][j] = fmaf(a[i], b[j], acc[i][j]);
        }
        __syncthreads();
    }

    #pragma unroll
    for (int i = 0; i < 4; ++i) {
        const int row = brow + ty * 4 + i;
        float4 o;
        o.x = acc[i][0] + bias[bcol + tx * 4 + 0];
        o.y = acc[i][1] + bias[bcol + tx * 4 + 1];
        o.z = acc[i][2] + bias[bcol + tx * 4 + 2];
        o.w = acc[i][3] + bias[bcol + tx * 4 + 3];
        *(float4*)(C + (size_t)row * N + bcol + tx * 4) = o;
    }
}

// ---------------- Flash attention (fp32), one block = (b, h, 64 q-rows) ----
#define QT 64
#define KTILE 64
#define PADDK (DK + 4)      // +4 floats keeps float4 alignment, kills 16-way bank conflict
#define PADKT (KTILE + 4)

__global__ __launch_bounds__(256) void attn_k(
    const float* __restrict__ q, const float* __restrict__ k,
    const float* __restrict__ v, float* __restrict__ ctx)
{
    __shared__ float Qs[QT][PADDK];
    __shared__ float Ks[KTILE][PADDK];
    __shared__ float Vs[KTILE][PADDK];
    __shared__ float Ps[QT][PADKT];
    __shared__ float rowm[QT], rowl[QT], rowsc[QT];

    const int tid = threadIdx.x;       // 256
    const int tx = tid & 15;           // col group (0..15)
    const int ty = tid >> 4;           // row group (0..15)
    const int qt = blockIdx.x, h = blockIdx.y, b = blockIdx.z;

    const size_t headoff = (size_t)h * DK;
    const float* qbase = q + (size_t)(b * SEQ + qt * QT) * D_MODEL + headoff;
    const float* kbase = k + (size_t)b * SEQ * D_MODEL + headoff;
    const float* vbase = v + (size_t)b * SEQ * D_MODEL + headoff;

    // Load Q tile (64x64): 16 lanes cover one 256B row, 4 rows per pass.
    {
        const int r0 = tid >> 4;           // 0..15
        const int c4 = (tid & 15) << 2;    // 0..60
        #pragma unroll
        for (int rr = 0; rr < 4; ++rr) {
            int r = r0 + rr * 16;
            *(float4*)&Qs[r][c4] = *(const float4*)(qbase + (size_t)r * D_MODEL + c4);
        }
    }
    if (tid < QT) { rowm[tid] = -INFINITY; rowl[tid] = 0.f; }

    float accO[4][4] = {};

    for (int kt = 0; kt < SEQ / KTILE; ++kt) {
        __syncthreads();   // previous PV done; Q load done (first iter)
        {
            const int r0 = tid >> 4;
            const int c4 = (tid & 15) << 2;
            const float* kp = kbase + (size_t)(kt * KTILE) * D_MODEL;
            const float* vp = vbase + (size_t)(kt * KTILE) * D_MODEL;
            #pragma unroll
            for (int rr = 0; rr < 4; ++rr) {
                int r = r0 + rr * 16;
                *(float4*)&Ks[r][c4] = *(const float4*)(kp + (size_t)r * D_MODEL + c4);
                *(float4*)&Vs[r][c4] = *(const float4*)(vp + (size_t)r * D_MODEL + c4);
            }
        }
        __syncthreads();

        // S = (Q @ K^T) * 1/8 ; thread owns rows ty*4..+4, cols tx*4..+4
        {
            float s[4][4] = {};
            for (int d = 0; d < DK; d += 4) {
                float qr[4][4], kr[4][4];
                #pragma unroll
                for (int i = 0; i < 4; ++i)
                    *(float4*)qr[i] = *(const float4*)&Qs[ty * 4 + i][d];
                #pragma unroll
                for (int j = 0; j < 4; ++j)
                    *(float4*)kr[j] = *(const float4*)&Ks[tx * 4 + j][d];
                #pragma unroll
                for (int i = 0; i < 4; ++i)
                    #pragma unroll
                    for (int j = 0; j < 4; ++j)
                        #pragma unroll
                        for (int dd = 0; dd < 4; ++dd)
                            s[i][j] = fmaf(qr[i][dd], kr[j][dd], s[i][j]);
            }
            #pragma unroll
            for (int i = 0; i < 4; ++i) {
                float4 o;
                o.x = s[i][0] * 0.125f;
                o.y = s[i][1] * 0.125f;
                o.z = s[i][2] * 0.125f;
                o.w = s[i][3] * 0.125f;
                *(float4*)&Ps[ty * 4 + i][tx * 4] = o;
            }
        }
        __syncthreads();

        // Online softmax: 4 threads per row, interleaved columns.
        {
            const int row = tid >> 2;      // 0..63
            const int sub = tid & 3;       // 0..3
            const float m_old = rowm[row];
            float mx = -INFINITY;
            #pragma unroll
            for (int cc = 0; cc < 16; ++cc)
                mx = fmaxf(mx, Ps[row][sub + cc * 4]);
            mx = fmaxf(mx, __shfl_xor(mx, 1));
            mx = fmaxf(mx, __shfl_xor(mx, 2));
            mx = fmaxf(mx, m_old);

            float lsum = 0.f;
            #pragma unroll
            for (int cc = 0; cc < 16; ++cc) {
                int c = sub + cc * 4;
                float p = __expf(Ps[row][c] - mx);
                Ps[row][c] = p;
                lsum += p;
            }
            lsum += __shfl_xor(lsum, 1);
            lsum += __shfl_xor(lsum, 2);
            if (sub == 0) {
                float sc = __expf(m_old - mx);
                rowsc[row] = sc;
                rowl[row] = rowl[row] * sc + lsum;
                rowm[row] = mx;
            }
        }
        __syncthreads();

        // accO = accO * rowsc + P @ V
        {
            float sc[4];
            #pragma unroll
            for (int i = 0; i < 4; ++i) sc[i] = rowsc[ty * 4 + i];
            #pragma unroll
            for (int i = 0; i < 4; ++i)
                #pragma unroll
                for (int j = 0; j < 4; ++j)
                    accO[i][j] *= sc[i];

            for (int c = 0; c < KTILE; c += 4) {
                float pr[4][4], vr[4][4];
                #pragma unroll
                for (int i = 0; i < 4; ++i)
                    *(float4*)pr[i] = *(const float4*)&Ps[ty * 4 + i][c];
                #pragma unroll
                for (int cc = 0; cc < 4; ++cc)
                    *(float4*)vr[cc] = *(const float4*)&Vs[c + cc][tx * 4];
                #pragma unroll
                for (int i = 0; i < 4; ++i)
                    #pragma unroll
                    for (int j = 0; j < 4; ++j)
                        #pragma unroll
                        for (int cc = 0; cc < 4; ++cc)
                            accO[i][j] = fmaf(pr[i][cc], vr[cc][j], accO[i][j]);
            }
        }
    }
    __syncthreads();

    // Normalize and store context in [B,S,D] layout (head-interleaved).
    {
        float* cbase = ctx + (size_t)(b * SEQ + qt * QT) * D_MODEL + headoff;
        #pragma unroll
        for (int i = 0; i < 4; ++i) {
            const int r = ty * 4 + i;
            const float inv = 1.f / rowl[r];
            float4 o;
            o.x = accO[i][0] * inv;
            o.y = accO[i][1] * inv;
            o.z = accO[i][2] * inv;
            o.w = accO[i][3] * inv;
            *(float4*)(cbase + (size_t)r * D_MODEL + tx * 4) = o;
        }
    }
}

// ---------------------------------------------------------------------------
extern "C" void kernel_launch(void* const* d_in, const int* in_sizes, int n_in,
                              void* d_out, int out_size, void* d_ws, size_t ws_size,
                              hipStream_t stream) {
    const float* query = (const float*)d_in[0];
    const float* key   = (const float*)d_in[1];
    const float* value = (const float*)d_in[2];
    const float* Wq = (const float*)d_in[3];
    const float* bq = (const float*)d_in[4];
    const float* Wk = (const float*)d_in[5];
    const float* bk = (const float*)d_in[6];
    const float* Wv = (const float*)d_in[7];
    const float* bv = (const float*)d_in[8];
    const float* Wo = (const float*)d_in[9];
    const float* bo = (const float*)d_in[10];
    float* out = (float*)d_out;

    const size_t mat = (size_t)MTOT * D_MODEL;   // 3.1M floats = 12.6 MB
    float* q   = (float*)d_ws;
    float* k   = q + mat;
    float* v   = k + mat;
    float* ctx = v + mat;

    dim3 gg(D_MODEL / GBN, MTOT / GBM);   // (12, 64)
    gemm_bias_k<<<gg, 256, 0, stream>>>(query, Wq, bq, q, MTOT, D_MODEL, D_MODEL);
    gemm_bias_k<<<gg, 256, 0, stream>>>(key,   Wk, bk, k, MTOT, D_MODEL, D_MODEL);
    gemm_bias_k<<<gg, 256, 0, stream>>>(value, Wv, bv, v, MTOT, D_MODEL, D_MODEL);

    attn_k<<<dim3(SEQ / QT, HEADS, BATCH), 256, 0, stream>>>(q, k, v, ctx);

    gemm_bias_k<<<gg, 256, 0, stream>>>(ctx, Wo, bo, out, MTOT, D_MODEL, D_MODEL);
}

// Round 2
// 434.498 us; speedup vs baseline: 1.7624x; 1.7624x over previous
//
#include <hip/hip_runtime.h>
#include <hip/hip_bf16.h>
#include <math.h>

#define D_MODEL 768
#define HEADS 12
#define DK 64
#define SEQ 2048
#define BATCH 2
#define MTOT (BATCH * SEQ)   // 4096

using short8 = __attribute__((ext_vector_type(8))) short;
using f32x4  = __attribute__((ext_vector_type(4))) float;

// ---------------- GEMM: C[M,N] = A[M,K] @ W[K,N] + bias[N] (all fp32) -------
#define GBM 64
#define GBN 64
#define GBK 16

__global__ __launch_bounds__(256) void gemm_bias_k(
    const float* __restrict__ A, const float* __restrict__ W,
    const float* __restrict__ bias, float* __restrict__ C,
    int M, int N, int K)
{
    __shared__ float As[GBK][GBM];   // transposed A tile: As[k][m]
    __shared__ float Bs[GBK][GBN];

    const int tid = threadIdx.x;            // 256 threads
    const int tx = tid & 15;                // 0..15 (N direction)
    const int ty = tid >> 4;                // 0..15 (M direction)
    const int brow = blockIdx.y * GBM;
    const int bcol = blockIdx.x * GBN;

    const int ar = tid >> 2;                // 0..63
    const int ac = (tid & 3) << 2;          // 0,4,8,12
    const int br = tid >> 4;                // 0..15
    const int bc = (tid & 15) << 2;         // 0..60

    float acc[4][4] = {};

    for (int k0 = 0; k0 < K; k0 += GBK) {
        float4 av = *(const float4*)(A + (size_t)(brow + ar) * K + k0 + ac);
        float4 bv = *(const float4*)(W + (size_t)(k0 + br) * N + bcol + bc);
        As[ac + 0][ar] = av.x;
        As[ac + 1][ar] = av.y;
        As[ac + 2][ar] = av.z;
        As[ac + 3][ar] = av.w;
        *(float4*)&Bs[br][bc] = bv;
        __syncthreads();

        #pragma unroll
        for (int kk = 0; kk < GBK; ++kk) {
            float a[4], b[4];
            *(float4*)a = *(const float4*)&As[kk][ty * 4];
            *(float4*)b = *(const float4*)&Bs[kk][tx * 4];
            #pragma unroll
            for (int i = 0; i < 4; ++i)
                #pragma unroll
                for (int j = 0; j < 4; ++j)
                    acc[i][j] = fmaf(a[i], b[j], acc[i][j]);
        }
        __syncthreads();
    }

    #pragma unroll
    for (int i = 0; i < 4; ++i) {
        const int row = brow + ty * 4 + i;
        float4 o;
        o.x = acc[i][0] + bias[bcol + tx * 4 + 0];
        o.y = acc[i][1] + bias[bcol + tx * 4 + 1];
        o.z = acc[i][2] + bias[bcol + tx * 4 + 2];
        o.w = acc[i][3] + bias[bcol + tx * 4 + 3];
        *(float4*)(C + (size_t)row * N + bcol + tx * 4) = o;
    }
}

// ---------------- bf16 helpers ---------------------------------------------
static __device__ __forceinline__ unsigned f2bf2(float x, float y) {
    __hip_bfloat162 t = __float22bfloat162_rn(float2{x, y});
    return *reinterpret_cast<unsigned*>(&t);
}
static __device__ __forceinline__ unsigned short f2bf1(float x) {
    __hip_bfloat16 t = __float2bfloat16(x);
    return *reinterpret_cast<unsigned short*>(&t);
}
static __device__ __forceinline__ short8 cvt8(float4 a, float4 b) {
    union { unsigned u[4]; short8 s; } r;
    r.u[0] = f2bf2(a.x, a.y);
    r.u[1] = f2bf2(a.z, a.w);
    r.u[2] = f2bf2(b.x, b.y);
    r.u[3] = f2bf2(b.z, b.w);
    return r.s;
}

// XOR swizzle: row-major [*][64] bf16 tile (128 B rows); flips 16B slot by row&7
#define SW(row, byteoff) (((row) << 7) + ((byteoff) ^ (((row) & 7) << 4)))

// ---------------- Flash attention, bf16 MFMA --------------------------------
// grid (32, 12, 2), 256 threads = 4 waves; wave w owns q-rows [16w, 16w+16)
__global__ __launch_bounds__(256) void attn_mfma_k(
    const float* __restrict__ q, const float* __restrict__ k,
    const float* __restrict__ v, float* __restrict__ ctx)
{
    __shared__ unsigned short lds_k[64 * 64];     // [key][d]  bf16, swizzled
    __shared__ unsigned short lds_v[64 * 64];     // [d][key]  bf16 (transposed), swizzled
    __shared__ unsigned short lds_p[4][16 * 64];  // per-wave P strip [row][key], swizzled

    const int tid  = threadIdx.x;
    const int w    = tid >> 6;        // wave 0..3
    const int lane = tid & 63;
    const int g    = lane >> 4;       // 0..3
    const int c    = lane & 15;       // 0..15
    const int qt = blockIdx.x, h = blockIdx.y, b = blockIdx.z;
    const int q0 = qt * 64;

    // ---- Q strip A-frags (held in registers for the whole kernel) ----
    // A layout (16x16x32): row = lane&15, k = (lane>>4)*8 + i
    short8 qf0, qf1;
    {
        const int qrow = q0 + (w << 4) + c;
        const float* qp = q + (size_t)(b * SEQ + qrow) * D_MODEL + h * DK;
        float4 a0 = *(const float4*)(qp + g * 8);
        float4 a1 = *(const float4*)(qp + g * 8 + 4);
        float4 a2 = *(const float4*)(qp + 32 + g * 8);
        float4 a3 = *(const float4*)(qp + 32 + g * 8 + 4);
        qf0 = cvt8(a0, a1);
        qf1 = cvt8(a2, a3);
    }

    // online-softmax state: rows 4g+reg (replicated across the 16 lanes of group g)
    float m_run[4] = {-INFINITY, -INFINITY, -INFINITY, -INFINITY};
    float l_run[4] = {0.f, 0.f, 0.f, 0.f};
    f32x4 o[4] = {f32x4{0,0,0,0}, f32x4{0,0,0,0}, f32x4{0,0,0,0}, f32x4{0,0,0,0}};

    // staging indices
    const int kr  = tid >> 2;              // K stage: row 0..63
    const int kc16 = (tid & 3) << 4;       // K stage: d0 in {0,16,32,48}
    const int vr0 = (tid & 15) << 2;       // V stage: key rows vr0..vr0+3
    const int vd0 = (tid >> 4) << 2;       // V stage: d cols vd0..vd0+3

    const float* kbase = k + (size_t)(b * SEQ) * D_MODEL + h * DK;
    const float* vbase = v + (size_t)(b * SEQ) * D_MODEL + h * DK;

    for (int kt = 0; kt < SEQ / 64; ++kt) {
        __syncthreads();   // previous iteration's LDS reads complete

        // ---- stage K tile (64 keys x 64 d) as bf16, swizzled ----
        {
            const float* kp = kbase + (size_t)(kt * 64 + kr) * D_MODEL + kc16;
            float4 k0 = *(const float4*)(kp + 0);
            float4 k1 = *(const float4*)(kp + 4);
            float4 k2 = *(const float4*)(kp + 8);
            float4 k3 = *(const float4*)(kp + 12);
            *(short8*)((char*)lds_k + SW(kr, 2 * kc16))      = cvt8(k0, k1);
            *(short8*)((char*)lds_k + SW(kr, 2 * kc16 + 16)) = cvt8(k2, k3);
        }
        // ---- stage V tile transposed: lds_v[d][key] ----
        {
            const float* vp = vbase + (size_t)(kt * 64 + vr0) * D_MODEL + vd0;
            float4 r0v = *(const float4*)(vp);
            float4 r1v = *(const float4*)(vp + D_MODEL);
            float4 r2v = *(const float4*)(vp + 2 * D_MODEL);
            float4 r3v = *(const float4*)(vp + 3 * D_MODEL);
            #pragma unroll
            for (int j = 0; j < 4; ++j) {
                uint2 pk;
                pk.x = f2bf2(((const float*)&r0v)[j], ((const float*)&r1v)[j]);
                pk.y = f2bf2(((const float*)&r2v)[j], ((const float*)&r3v)[j]);
                *(uint2*)((char*)lds_v + SW(vd0 + j, 2 * vr0)) = pk;
            }
        }
        __syncthreads();

        // ---- S = Q @ K^T : 8 MFMA into 4 accumulators (16 q-rows x 64 keys) ----
        f32x4 sacc[4] = {f32x4{0,0,0,0}, f32x4{0,0,0,0}, f32x4{0,0,0,0}, f32x4{0,0,0,0}};
        #pragma unroll
        for (int kstep = 0; kstep < 2; ++kstep) {
            short8 af = kstep ? qf1 : qf0;
            #pragma unroll
            for (int ks = 0; ks < 4; ++ks) {
                short8 bf = *(const short8*)((const char*)lds_k +
                             SW(ks * 16 + c, kstep * 64 + g * 16));
                sacc[ks] = __builtin_amdgcn_mfma_f32_16x16x32_bf16(af, bf, sacc[ks], 0, 0, 0);
            }
        }

        // ---- online softmax in registers; write P (bf16) to per-wave LDS ----
        #pragma unroll
        for (int reg = 0; reg < 4; ++reg) {
            float s0 = sacc[0][reg] * 0.125f;
            float s1 = sacc[1][reg] * 0.125f;
            float s2 = sacc[2][reg] * 0.125f;
            float s3 = sacc[3][reg] * 0.125f;
            float mx = fmaxf(fmaxf(s0, s1), fmaxf(s2, s3));
            mx = fmaxf(mx, __shfl_xor(mx, 1));
            mx = fmaxf(mx, __shfl_xor(mx, 2));
            mx = fmaxf(mx, __shfl_xor(mx, 4));
            mx = fmaxf(mx, __shfl_xor(mx, 8));
            const float mnew = fmaxf(m_run[reg], mx);
            const float sc = __expf(m_run[reg] - mnew);
            m_run[reg] = mnew;
            float p0 = __expf(s0 - mnew);
            float p1 = __expf(s1 - mnew);
            float p2 = __expf(s2 - mnew);
            float p3 = __expf(s3 - mnew);
            float ps = p0 + p1 + p2 + p3;
            ps += __shfl_xor(ps, 1);
            ps += __shfl_xor(ps, 2);
            ps += __shfl_xor(ps, 4);
            ps += __shfl_xor(ps, 8);
            l_run[reg] = l_run[reg] * sc + ps;
            o[0][reg] *= sc;
            o[1][reg] *= sc;
            o[2][reg] *= sc;
            o[3][reg] *= sc;
            const int prow = (g << 2) + reg;
            *(unsigned short*)((char*)lds_p[w] + SW(prow, 2 * (0 * 16 + c))) = f2bf1(p0);
            *(unsigned short*)((char*)lds_p[w] + SW(prow, 2 * (1 * 16 + c))) = f2bf1(p1);
            *(unsigned short*)((char*)lds_p[w] + SW(prow, 2 * (2 * 16 + c))) = f2bf1(p2);
            *(unsigned short*)((char*)lds_p[w] + SW(prow, 2 * (3 * 16 + c))) = f2bf1(p3);
        }

        // ---- O += P @ V : 8 MFMA (per-wave P, block-shared V_t) ----
        #pragma unroll
        for (int kstep = 0; kstep < 2; ++kstep) {
            short8 paf = *(const short8*)((const char*)lds_p[w] +
                          SW(c, kstep * 64 + g * 16));
            #pragma unroll
            for (int dsub = 0; dsub < 4; ++dsub) {
                short8 vbf = *(const short8*)((const char*)lds_v +
                              SW(dsub * 16 + c, kstep * 64 + g * 16));
                o[dsub] = __builtin_amdgcn_mfma_f32_16x16x32_bf16(paf, vbf, o[dsub], 0, 0, 0);
            }
        }
    }

    // ---- normalize and store context (fp32, [B*S][D] head-interleaved) ----
    #pragma unroll
    for (int reg = 0; reg < 4; ++reg) {
        const int qrow = q0 + (w << 4) + (g << 2) + reg;
        float* cb = ctx + (size_t)(b * SEQ + qrow) * D_MODEL + h * DK;
        const float invl = 1.f / l_run[reg];
        #pragma unroll
        for (int dsub = 0; dsub < 4; ++dsub)
            cb[dsub * 16 + c] = o[dsub][reg] * invl;
    }
}

// ---------------------------------------------------------------------------
extern "C" void kernel_launch(void* const* d_in, const int* in_sizes, int n_in,
                              void* d_out, int out_size, void* d_ws, size_t ws_size,
                              hipStream_t stream) {
    const float* query = (const float*)d_in[0];
    const float* key   = (const float*)d_in[1];
    const float* value = (const float*)d_in[2];
    const float* Wq = (const float*)d_in[3];
    const float* bq = (const float*)d_in[4];
    const float* Wk = (const float*)d_in[5];
    const float* bk = (const float*)d_in[6];
    const float* Wv = (const float*)d_in[7];
    const float* bv = (const float*)d_in[8];
    const float* Wo = (const float*)d_in[9];
    const float* bo = (const float*)d_in[10];
    float* out = (float*)d_out;

    const size_t mat = (size_t)MTOT * D_MODEL;   // 3.1M floats = 12.6 MB
    float* q   = (float*)d_ws;
    float* k   = q + mat;
    float* v   = k + mat;
    float* ctx = v + mat;

    dim3 gg(D_MODEL / GBN, MTOT / GBM);   // (12, 64)
    gemm_bias_k<<<gg, 256, 0, stream>>>(query, Wq, bq, q, MTOT, D_MODEL, D_MODEL);
    gemm_bias_k<<<gg, 256, 0, stream>>>(key,   Wk, bk, k, MTOT, D_MODEL, D_MODEL);
    gemm_bias_k<<<gg, 256, 0, stream>>>(value, Wv, bv, v, MTOT, D_MODEL, D_MODEL);

    attn_mfma_k<<<dim3(SEQ / 64, HEADS, BATCH), 256, 0, stream>>>(q, k, v, ctx);

    gemm_bias_k<<<gg, 256, 0, stream>>>(ctx, Wo, bo, out, MTOT, D_MODEL, D_MODEL);
}

// Round 3
// 175.901 us; speedup vs baseline: 4.3534x; 2.4701x over previous
//
#include <hip/hip_runtime.h>
#include <hip/hip_bf16.h>
#include <math.h>

#define D_MODEL 768
#define HEADS 12
#define DK 64
#define SEQ 2048
#define BATCH 2
#define MTOT (BATCH * SEQ)   // 4096

using short8 = __attribute__((ext_vector_type(8))) short;
using us4    = __attribute__((ext_vector_type(4))) unsigned short;
using f32x4  = __attribute__((ext_vector_type(4))) float;

// ---------------- bf16 helpers ---------------------------------------------
static __device__ __forceinline__ unsigned f2bf2(float x, float y) {
    __hip_bfloat162 t = __float22bfloat162_rn(float2{x, y});
    return *reinterpret_cast<unsigned*>(&t);
}
static __device__ __forceinline__ unsigned short f2bf1(float x) {
    __hip_bfloat16 t = __float2bfloat16(x);
    return *reinterpret_cast<unsigned short*>(&t);
}

// XOR swizzle for 128-byte LDS rows: flips 16B slot by row&7 (2-way worst case)
#define SW(row, byteoff) (((row) << 7) + ((byteoff) ^ (((row) & 7) << 4)))

// async global->LDS, 16B per lane; lds dst must be wave-uniform
static __device__ __forceinline__ void gload_lds16(const void* g, void* l) {
    __builtin_amdgcn_global_load_lds(
        (const __attribute__((address_space(1))) void*)g,
        (__attribute__((address_space(3))) void*)l, 16, 0, 0);
}

// ---------------- pre-pass: fp32 -> bf16 ------------------------------------
__global__ __launch_bounds__(256) void cvt_bf16_k(
    const float* __restrict__ x, unsigned short* __restrict__ y, int n8)
{
    int i = blockIdx.x * 256 + threadIdx.x;
    if (i >= n8) return;
    const float4* xp = (const float4*)x;
    float4 a = xp[2 * i], b = xp[2 * i + 1];
    union { unsigned u[4]; short8 s; } r;
    r.u[0] = f2bf2(a.x, a.y);
    r.u[1] = f2bf2(a.z, a.w);
    r.u[2] = f2bf2(b.x, b.y);
    r.u[3] = f2bf2(b.z, b.w);
    ((short8*)y)[i] = r.s;
}

// ---------------- pre-pass: W[k][n] fp32 -> Wt[n][k] bf16 -------------------
__global__ __launch_bounds__(256) void cvt_wt_k(
    const float* __restrict__ W, unsigned short* __restrict__ Wt)
{
    __shared__ float t[32][33];
    const int n0 = blockIdx.x * 32, k0 = blockIdx.y * 32;
    const int tx = threadIdx.x & 31;
    const int ty0 = (threadIdx.x >> 5) * 4;   // 0,4,..,28
    #pragma unroll
    for (int j = 0; j < 4; ++j)
        t[ty0 + j][tx] = W[(size_t)(k0 + ty0 + j) * D_MODEL + n0 + tx];
    __syncthreads();
    #pragma unroll
    for (int j = 0; j < 4; ++j)
        Wt[(size_t)(n0 + ty0 + j) * D_MODEL + k0 + tx] = f2bf1(t[tx][ty0 + j]);
}

// ---------------- bf16 MFMA GEMM: C[M,768] = A[M,768] @ Wt^T + bias ---------
// A[m][k] bf16, Wt[n][k] bf16. 64x64 tile, BK=64, 256 thr = 4 waves (2x2).
template <int OUT_BF16>
__global__ __launch_bounds__(256) void gemm_mfma_k(
    const unsigned short* __restrict__ A, const unsigned short* __restrict__ Wt,
    const float* __restrict__ bias, void* __restrict__ C)
{
    __shared__ unsigned short As[64 * 64];   // [m][k] swizzled, 8 KB
    __shared__ unsigned short Bs[64 * 64];   // [n][k] swizzled, 8 KB

    const int tid  = threadIdx.x;
    const int w    = tid >> 6;
    const int lane = tid & 63;
    const int g    = lane >> 4, c = lane & 15;
    const int wr   = w >> 1, wc = w & 1;
    const int brow = blockIdx.y * 64;
    const int bcol = blockIdx.x * 64;

    f32x4 acc[2][2] = {{f32x4{0,0,0,0}, f32x4{0,0,0,0}},
                       {f32x4{0,0,0,0}, f32x4{0,0,0,0}}};

    // staging geometry (per wave, 2 rounds x 1KB): linear dest + pre-swizzled src
    int srow[2], soff[2], sbase[2];
    #pragma unroll
    for (int r = 0; r < 2; ++r) {
        int phys = (w + 4 * r) * 1024 + lane * 16;
        int row  = phys >> 7;
        int slot = (phys >> 4) & 7;
        int log  = slot ^ (row & 7);
        srow[r]  = row;
        soff[r]  = log * 8;              // elems within the 64-elem row
        sbase[r] = (w + 4 * r) * 1024;   // wave-uniform LDS byte base
    }

    for (int k0 = 0; k0 < D_MODEL; k0 += 64) {
        __syncthreads();   // previous compute done before overwriting LDS
        #pragma unroll
        for (int r = 0; r < 2; ++r) {
            gload_lds16(A  + (size_t)(brow + srow[r]) * D_MODEL + k0 + soff[r],
                        (char*)As + sbase[r]);
            gload_lds16(Wt + (size_t)(bcol + srow[r]) * D_MODEL + k0 + soff[r],
                        (char*)Bs + sbase[r]);
        }
        __syncthreads();   // drains vmcnt + lgkmcnt

        #pragma unroll
        for (int kstep = 0; kstep < 2; ++kstep) {
            short8 af[2], bf[2];
            #pragma unroll
            for (int m = 0; m < 2; ++m)
                af[m] = *(const short8*)((const char*)As +
                         SW(wr * 32 + m * 16 + c, kstep * 64 + g * 16));
            #pragma unroll
            for (int n = 0; n < 2; ++n)
                bf[n] = *(const short8*)((const char*)Bs +
                         SW(wc * 32 + n * 16 + c, kstep * 64 + g * 16));
            #pragma unroll
            for (int m = 0; m < 2; ++m)
                #pragma unroll
                for (int n = 0; n < 2; ++n)
                    acc[m][n] = __builtin_amdgcn_mfma_f32_16x16x32_bf16(
                                    af[m], bf[n], acc[m][n], 0, 0, 0);
        }
    }

    #pragma unroll
    for (int m = 0; m < 2; ++m)
        #pragma unroll
        for (int n = 0; n < 2; ++n) {
            const int col = bcol + wc * 32 + n * 16 + c;
            const float bval = bias[col];
            #pragma unroll
            for (int j = 0; j < 4; ++j) {
                const int row = brow + wr * 32 + m * 16 + g * 4 + j;
                const float val = acc[m][n][j] + bval;
                if (OUT_BF16)
                    ((unsigned short*)C)[(size_t)row * D_MODEL + col] = f2bf1(val);
                else
                    ((float*)C)[(size_t)row * D_MODEL + col] = val;
            }
        }
}

// ---------------- Flash attention, bf16 in / bf16 out -----------------------
// grid (32, 12, 2), 256 threads = 4 waves; wave w owns q-rows [16w, 16w+16)
__global__ __launch_bounds__(256) void attn_mfma_k(
    const unsigned short* __restrict__ q, const unsigned short* __restrict__ k,
    const unsigned short* __restrict__ v, unsigned short* __restrict__ ctx)
{
    __shared__ unsigned short lds_k[64 * 64];     // [key][d]  swizzled
    __shared__ unsigned short lds_v[64 * 64];     // [d][key]  transposed, swizzled
    __shared__ unsigned short lds_p[4][16 * 64];  // per-wave P strip, swizzled

    const int tid  = threadIdx.x;
    const int w    = tid >> 6;
    const int lane = tid & 63;
    const int g    = lane >> 4;
    const int c    = lane & 15;
    const int qt = blockIdx.x, h = blockIdx.y, b = blockIdx.z;
    const int q0 = qt * 64;

    // Q strip A-frags (registers, whole kernel)
    short8 qf0, qf1;
    {
        const int qrow = q0 + (w << 4) + c;
        const unsigned short* qp = q + (size_t)(b * SEQ + qrow) * D_MODEL + h * DK;
        qf0 = *(const short8*)(qp + g * 8);
        qf1 = *(const short8*)(qp + 32 + g * 8);
    }

    float m_run[4] = {-INFINITY, -INFINITY, -INFINITY, -INFINITY};
    float l_run[4] = {0.f, 0.f, 0.f, 0.f};
    f32x4 o[4] = {f32x4{0,0,0,0}, f32x4{0,0,0,0}, f32x4{0,0,0,0}, f32x4{0,0,0,0}};

    // K staging: global_load_lds, pre-swizzled source
    int ksrow[2], ksoff[2], ksbase[2];
    #pragma unroll
    for (int r = 0; r < 2; ++r) {
        int phys = (w + 4 * r) * 1024 + lane * 16;
        int row  = phys >> 7;
        int slot = (phys >> 4) & 7;
        ksrow[r] = row;
        ksoff[r] = (slot ^ (row & 7)) * 8;
        ksbase[r] = (w + 4 * r) * 1024;
    }
    // V staging (register transpose)
    const int vr0 = (tid & 15) << 2;       // 4 key rows
    const int vd0 = (tid >> 4) << 2;       // 4 d cols

    const unsigned short* kbase = k + (size_t)(b * SEQ) * D_MODEL + h * DK;
    const unsigned short* vbase = v + (size_t)(b * SEQ) * D_MODEL + h * DK;

    for (int kt = 0; kt < SEQ / 64; ++kt) {
        __syncthreads();

        #pragma unroll
        for (int r = 0; r < 2; ++r)
            gload_lds16(kbase + (size_t)(kt * 64 + ksrow[r]) * D_MODEL + ksoff[r],
                        (char*)lds_k + ksbase[r]);
        {
            const unsigned short* vp = vbase + (size_t)(kt * 64 + vr0) * D_MODEL + vd0;
            us4 r0 = *(const us4*)(vp);
            us4 r1 = *(const us4*)(vp + D_MODEL);
            us4 r2 = *(const us4*)(vp + 2 * D_MODEL);
            us4 r3 = *(const us4*)(vp + 3 * D_MODEL);
            #pragma unroll
            for (int j = 0; j < 4; ++j) {
                uint2 pk;
                pk.x = (unsigned)r0[j] | ((unsigned)r1[j] << 16);
                pk.y = (unsigned)r2[j] | ((unsigned)r3[j] << 16);
                *(uint2*)((char*)lds_v + SW(vd0 + j, 2 * vr0)) = pk;
            }
        }
        __syncthreads();

        // S = Q @ K^T
        f32x4 sacc[4] = {f32x4{0,0,0,0}, f32x4{0,0,0,0}, f32x4{0,0,0,0}, f32x4{0,0,0,0}};
        #pragma unroll
        for (int kstep = 0; kstep < 2; ++kstep) {
            short8 af = kstep ? qf1 : qf0;
            #pragma unroll
            for (int ks = 0; ks < 4; ++ks) {
                short8 bf = *(const short8*)((const char*)lds_k +
                             SW(ks * 16 + c, kstep * 64 + g * 16));
                sacc[ks] = __builtin_amdgcn_mfma_f32_16x16x32_bf16(af, bf, sacc[ks], 0, 0, 0);
            }
        }

        // online softmax (registers) -> P bf16 to per-wave LDS
        #pragma unroll
        for (int reg = 0; reg < 4; ++reg) {
            float s0 = sacc[0][reg] * 0.125f;
            float s1 = sacc[1][reg] * 0.125f;
            float s2 = sacc[2][reg] * 0.125f;
            float s3 = sacc[3][reg] * 0.125f;
            float mx = fmaxf(fmaxf(s0, s1), fmaxf(s2, s3));
            mx = fmaxf(mx, __shfl_xor(mx, 1));
            mx = fmaxf(mx, __shfl_xor(mx, 2));
            mx = fmaxf(mx, __shfl_xor(mx, 4));
            mx = fmaxf(mx, __shfl_xor(mx, 8));
            const float mnew = fmaxf(m_run[reg], mx);
            const float sc = __expf(m_run[reg] - mnew);
            m_run[reg] = mnew;
            float p0 = __expf(s0 - mnew);
            float p1 = __expf(s1 - mnew);
            float p2 = __expf(s2 - mnew);
            float p3 = __expf(s3 - mnew);
            float ps = p0 + p1 + p2 + p3;
            ps += __shfl_xor(ps, 1);
            ps += __shfl_xor(ps, 2);
            ps += __shfl_xor(ps, 4);
            ps += __shfl_xor(ps, 8);
            l_run[reg] = l_run[reg] * sc + ps;
            o[0][reg] *= sc;
            o[1][reg] *= sc;
            o[2][reg] *= sc;
            o[3][reg] *= sc;
            const int prow = (g << 2) + reg;
            *(unsigned short*)((char*)lds_p[w] + SW(prow, 2 * (0 * 16 + c))) = f2bf1(p0);
            *(unsigned short*)((char*)lds_p[w] + SW(prow, 2 * (1 * 16 + c))) = f2bf1(p1);
            *(unsigned short*)((char*)lds_p[w] + SW(prow, 2 * (2 * 16 + c))) = f2bf1(p2);
            *(unsigned short*)((char*)lds_p[w] + SW(prow, 2 * (3 * 16 + c))) = f2bf1(p3);
        }

        // O += P @ V
        #pragma unroll
        for (int kstep = 0; kstep < 2; ++kstep) {
            short8 paf = *(const short8*)((const char*)lds_p[w] +
                          SW(c, kstep * 64 + g * 16));
            #pragma unroll
            for (int dsub = 0; dsub < 4; ++dsub) {
                short8 vbf = *(const short8*)((const char*)lds_v +
                              SW(dsub * 16 + c, kstep * 64 + g * 16));
                o[dsub] = __builtin_amdgcn_mfma_f32_16x16x32_bf16(paf, vbf, o[dsub], 0, 0, 0);
            }
        }
    }

    // normalize, store ctx as bf16
    #pragma unroll
    for (int reg = 0; reg < 4; ++reg) {
        const int qrow = q0 + (w << 4) + (g << 2) + reg;
        unsigned short* cb = ctx + (size_t)(b * SEQ + qrow) * D_MODEL + h * DK;
        const float invl = 1.f / l_run[reg];
        #pragma unroll
        for (int dsub = 0; dsub < 4; ++dsub)
            cb[dsub * 16 + c] = f2bf1(o[dsub][reg] * invl);
    }
}

// ---------------------------------------------------------------------------
extern "C" void kernel_launch(void* const* d_in, const int* in_sizes, int n_in,
                              void* d_out, int out_size, void* d_ws, size_t ws_size,
                              hipStream_t stream) {
    const float* query = (const float*)d_in[0];
    const float* key   = (const float*)d_in[1];
    const float* value = (const float*)d_in[2];
    const float* Wq = (const float*)d_in[3];
    const float* bq = (const float*)d_in[4];
    const float* Wk = (const float*)d_in[5];
    const float* bk = (const float*)d_in[6];
    const float* Wv = (const float*)d_in[7];
    const float* bv = (const float*)d_in[8];
    const float* Wo = (const float*)d_in[9];
    const float* bo = (const float*)d_in[10];
    float* out = (float*)d_out;

    const size_t mat = (size_t)MTOT * D_MODEL;      // 3.145M elems
    unsigned short* qx  = (unsigned short*)d_ws;    // bf16 inputs
    unsigned short* kx  = qx + mat;
    unsigned short* vx  = kx + mat;
    unsigned short* qb  = vx + mat;                 // projected Q/K/V (bf16)
    unsigned short* kb  = qb + mat;
    unsigned short* vb  = kb + mat;
    unsigned short* cb  = vb + mat;                 // context (bf16)
    unsigned short* Wqt = cb + mat;                 // transposed bf16 weights
    unsigned short* Wkt = Wqt + D_MODEL * D_MODEL;
    unsigned short* Wvt = Wkt + D_MODEL * D_MODEL;
    unsigned short* Wot = Wvt + D_MODEL * D_MODEL;

    const int n8 = (int)(mat / 8);
    cvt_bf16_k<<<(n8 + 255) / 256, 256, 0, stream>>>(query, qx, n8);
    cvt_bf16_k<<<(n8 + 255) / 256, 256, 0, stream>>>(key,   kx, n8);
    cvt_bf16_k<<<(n8 + 255) / 256, 256, 0, stream>>>(value, vx, n8);

    dim3 gt(D_MODEL / 32, D_MODEL / 32);
    cvt_wt_k<<<gt, 256, 0, stream>>>(Wq, Wqt);
    cvt_wt_k<<<gt, 256, 0, stream>>>(Wk, Wkt);
    cvt_wt_k<<<gt, 256, 0, stream>>>(Wv, Wvt);
    cvt_wt_k<<<gt, 256, 0, stream>>>(Wo, Wot);

    dim3 gg(D_MODEL / 64, MTOT / 64);   // (12, 64) = 768 blocks
    gemm_mfma_k<1><<<gg, 256, 0, stream>>>(qx, Wqt, bq, qb);
    gemm_mfma_k<1><<<gg, 256, 0, stream>>>(kx, Wkt, bk, kb);
    gemm_mfma_k<1><<<gg, 256, 0, stream>>>(vx, Wvt, bv, vb);

    attn_mfma_k<<<dim3(SEQ / 64, HEADS, BATCH), 256, 0, stream>>>(qb, kb, vb, cb);

    gemm_mfma_k<0><<<gg, 256, 0, stream>>>(cb, Wot, bo, out);
}

// Round 4
// 139.676 us; speedup vs baseline: 5.4825x; 1.2593x over previous
//
#include <hip/hip_runtime.h>
#include <hip/hip_bf16.h>
#include <math.h>

#define D_MODEL 768
#define HEADS 12
#define DK 64
#define SEQ 2048
#define BATCH 2
#define MTOT (BATCH * SEQ)   // 4096
#define QSCALE 0.18033688011112042f   // 0.125 * log2(e): Q pre-scale -> softmax in exp2 domain

using short8 = __attribute__((ext_vector_type(8))) short;
using us4    = __attribute__((ext_vector_type(4))) unsigned short;
using f32x4  = __attribute__((ext_vector_type(4))) float;

// ---------------- helpers ---------------------------------------------------
static __device__ __forceinline__ unsigned f2bf2(float x, float y) {
    __hip_bfloat162 t = __float22bfloat162_rn(float2{x, y});
    return *reinterpret_cast<unsigned*>(&t);
}
static __device__ __forceinline__ unsigned short f2bf1(float x) {
    __hip_bfloat16 t = __float2bfloat16(x);
    return *reinterpret_cast<unsigned short*>(&t);
}
static __device__ __forceinline__ float fast_exp2(float x) {
#if __has_builtin(__builtin_amdgcn_exp2f)
    return __builtin_amdgcn_exp2f(x);
#else
    return __expf(x * 0.6931471805599453f);
#endif
}

// XOR swizzle for 128-byte LDS rows: flips 16B slot by row&7
#define SW(row, byteoff) (((row) << 7) + ((byteoff) ^ (((row) & 7) << 4)))

// async global->LDS, 16B per lane; LDS dst wave-uniform base + lane*16
static __device__ __forceinline__ void gload_lds16(const void* g, void* l) {
    __builtin_amdgcn_global_load_lds(
        (const __attribute__((address_space(1))) void*)g,
        (__attribute__((address_space(3))) void*)l, 16, 0, 0);
}

// ---------------- pre-pass: fp32 -> bf16 (q,k,v fused via blockIdx.y) -------
__global__ __launch_bounds__(256) void cvt_in_k(
    const float* __restrict__ q, const float* __restrict__ k, const float* __restrict__ v,
    unsigned short* __restrict__ qx, unsigned short* __restrict__ kx,
    unsigned short* __restrict__ vx, int n8)
{
    const int z = blockIdx.y;
    const float* x = z == 0 ? q : z == 1 ? k : v;
    unsigned short* y = z == 0 ? qx : z == 1 ? kx : vx;
    int i = blockIdx.x * 256 + threadIdx.x;
    if (i >= n8) return;
    const float4* xp = (const float4*)x;
    float4 a = xp[2 * i], b = xp[2 * i + 1];
    union { unsigned u[4]; short8 s; } r;
    r.u[0] = f2bf2(a.x, a.y);
    r.u[1] = f2bf2(a.z, a.w);
    r.u[2] = f2bf2(b.x, b.y);
    r.u[3] = f2bf2(b.z, b.w);
    ((short8*)y)[i] = r.s;
}

// ---------------- pre-pass: W[k][n] fp32 -> Wt[n][k] bf16 (4 W's fused) -----
__global__ __launch_bounds__(256) void cvt_wt_k(
    const float* __restrict__ Wq, const float* __restrict__ Wk,
    const float* __restrict__ Wv, const float* __restrict__ Wo,
    unsigned short* __restrict__ Wqt, unsigned short* __restrict__ Wkt,
    unsigned short* __restrict__ Wvt, unsigned short* __restrict__ Wot)
{
    const int z = blockIdx.z;
    const float* W = z == 0 ? Wq : z == 1 ? Wk : z == 2 ? Wv : Wo;
    unsigned short* Wt = z == 0 ? Wqt : z == 1 ? Wkt : z == 2 ? Wvt : Wot;
    __shared__ float t[32][33];
    const int n0 = blockIdx.x * 32, k0 = blockIdx.y * 32;
    const int tx = threadIdx.x & 31;
    const int ty0 = (threadIdx.x >> 5) * 4;
    #pragma unroll
    for (int j = 0; j < 4; ++j)
        t[ty0 + j][tx] = W[(size_t)(k0 + ty0 + j) * D_MODEL + n0 + tx];
    __syncthreads();
    #pragma unroll
    for (int j = 0; j < 4; ++j)
        Wt[(size_t)(n0 + ty0 + j) * D_MODEL + k0 + tx] = f2bf1(t[tx][ty0 + j]);
}

// ---------------- bf16 MFMA GEMM body: 64x64 tile, BK=64, double-buffered ---
template <int OUT_BF16>
static __device__ __forceinline__ void gemm_body(
    const unsigned short* __restrict__ A, const unsigned short* __restrict__ Wt,
    const float* __restrict__ bias, void* __restrict__ C, float scale)
{
    __shared__ unsigned short As[2][64 * 64];   // [m][k] swizzled, 8 KB each
    __shared__ unsigned short Bs[2][64 * 64];   // [n][k] swizzled

    const int tid  = threadIdx.x;
    const int w    = tid >> 6;
    const int lane = tid & 63;
    const int g    = lane >> 4, c = lane & 15;
    const int wr   = w >> 1, wc = w & 1;
    const int brow = blockIdx.y * 64;
    const int bcol = blockIdx.x * 64;

    f32x4 acc[2][2] = {{f32x4{0,0,0,0}, f32x4{0,0,0,0}},
                       {f32x4{0,0,0,0}, f32x4{0,0,0,0}}};

    int srow[2], soff[2], sbase[2];
    #pragma unroll
    for (int r = 0; r < 2; ++r) {
        int phys = (w + 4 * r) * 1024 + lane * 16;
        int row  = phys >> 7;
        int slot = (phys >> 4) & 7;
        srow[r]  = row;
        soff[r]  = (slot ^ (row & 7)) * 8;
        sbase[r] = (w + 4 * r) * 1024;
    }

    auto stage = [&](int k0, int buf) {
        #pragma unroll
        for (int r = 0; r < 2; ++r) {
            gload_lds16(A  + (size_t)(brow + srow[r]) * D_MODEL + k0 + soff[r],
                        (char*)As + buf * 8192 + sbase[r]);
            gload_lds16(Wt + (size_t)(bcol + srow[r]) * D_MODEL + k0 + soff[r],
                        (char*)Bs + buf * 8192 + sbase[r]);
        }
    };

    stage(0, 0);
    __syncthreads();

    int cur = 0;
    for (int k0 = 0; k0 < D_MODEL; k0 += 64) {
        const int nxt = cur ^ 1;
        if (k0 + 64 < D_MODEL) stage(k0 + 64, nxt);   // async, overlaps compute

        #pragma unroll
        for (int kstep = 0; kstep < 2; ++kstep) {
            short8 af[2], bf[2];
            #pragma unroll
            for (int m = 0; m < 2; ++m)
                af[m] = *(const short8*)((const char*)As + cur * 8192 +
                         SW(wr * 32 + m * 16 + c, kstep * 64 + g * 16));
            #pragma unroll
            for (int n = 0; n < 2; ++n)
                bf[n] = *(const short8*)((const char*)Bs + cur * 8192 +
                         SW(wc * 32 + n * 16 + c, kstep * 64 + g * 16));
            #pragma unroll
            for (int m = 0; m < 2; ++m)
                #pragma unroll
                for (int n = 0; n < 2; ++n)
                    acc[m][n] = __builtin_amdgcn_mfma_f32_16x16x32_bf16(
                                    af[m], bf[n], acc[m][n], 0, 0, 0);
        }
        __syncthreads();   // drains staging vmcnt; protects cur for next overwrite
        cur = nxt;
    }

    #pragma unroll
    for (int m = 0; m < 2; ++m)
        #pragma unroll
        for (int n = 0; n < 2; ++n) {
            const int col = bcol + wc * 32 + n * 16 + c;
            const float bval = bias[col];
            #pragma unroll
            for (int j = 0; j < 4; ++j) {
                const int row = brow + wr * 32 + m * 16 + g * 4 + j;
                const float val = (acc[m][n][j] + bval) * scale;
                if (OUT_BF16)
                    ((unsigned short*)C)[(size_t)row * D_MODEL + col] = f2bf1(val);
                else
                    ((float*)C)[(size_t)row * D_MODEL + col] = val;
            }
        }
}

__global__ __launch_bounds__(256) void gemm_qkv_k(
    const unsigned short* __restrict__ qx, const unsigned short* __restrict__ kx,
    const unsigned short* __restrict__ vx,
    const unsigned short* __restrict__ Wqt, const unsigned short* __restrict__ Wkt,
    const unsigned short* __restrict__ Wvt,
    const float* __restrict__ bq, const float* __restrict__ bk,
    const float* __restrict__ bv,
    unsigned short* __restrict__ qb, unsigned short* __restrict__ kb,
    unsigned short* __restrict__ vb)
{
    const int z = blockIdx.z;
    const unsigned short* A  = z == 0 ? qx  : z == 1 ? kx  : vx;
    const unsigned short* Wt = z == 0 ? Wqt : z == 1 ? Wkt : Wvt;
    const float* bias        = z == 0 ? bq  : z == 1 ? bk  : bv;
    unsigned short* C        = z == 0 ? qb  : z == 1 ? kb  : vb;
    gemm_body<1>(A, Wt, bias, C, z == 0 ? QSCALE : 1.0f);
}

__global__ __launch_bounds__(256) void gemm_o_k(
    const unsigned short* __restrict__ A, const unsigned short* __restrict__ Wt,
    const float* __restrict__ bias, float* __restrict__ C)
{
    gemm_body<0>(A, Wt, bias, C, 1.0f);
}

// ---------------- Flash attention, bf16, double-buffered, defer-max ---------
// grid (32, 12, 2), 256 threads = 4 waves; wave w owns q-rows [16w, 16w+16)
// Key-axis permutation pi(key) = (key&15)*4 + (key>>4), applied identically to
// P-LDS and V^T-LDS (dot over keys is order-invariant) -> b64 P writes.
__global__ __launch_bounds__(256) void attn_mfma_k(
    const unsigned short* __restrict__ q, const unsigned short* __restrict__ k,
    const unsigned short* __restrict__ v, unsigned short* __restrict__ ctx)
{
    __shared__ unsigned short lds_k[2][64 * 64];   // [key][d] swizzled
    __shared__ unsigned short lds_v[2][64 * 64];   // [d][pi(key)] swizzled
    __shared__ unsigned short lds_p[4][16 * 64];   // per-wave [row][pi(key)] swizzled

    const int tid  = threadIdx.x;
    const int w    = tid >> 6;
    const int lane = tid & 63;
    const int g    = lane >> 4;
    const int c    = lane & 15;
    const int qt = blockIdx.x, h = blockIdx.y, b = blockIdx.z;
    const int q0 = qt * 64;

    // Q strip A-frags (pre-scaled by QSCALE in the projection GEMM)
    short8 qf0, qf1;
    {
        const int qrow = q0 + (w << 4) + c;
        const unsigned short* qp = q + (size_t)(b * SEQ + qrow) * D_MODEL + h * DK;
        qf0 = *(const short8*)(qp + g * 8);
        qf1 = *(const short8*)(qp + 32 + g * 8);
    }

    float m_run[4] = {-INFINITY, -INFINITY, -INFINITY, -INFINITY};
    float l_run[4] = {0.f, 0.f, 0.f, 0.f};
    f32x4 o[4] = {f32x4{0,0,0,0}, f32x4{0,0,0,0}, f32x4{0,0,0,0}, f32x4{0,0,0,0}};

    // K staging geometry (global_load_lds, pre-swizzled source)
    int ksrow[2], ksoff[2], ksbase[2];
    #pragma unroll
    for (int r = 0; r < 2; ++r) {
        int phys = (w + 4 * r) * 1024 + lane * 16;
        int row  = phys >> 7;
        int slot = (phys >> 4) & 7;
        ksrow[r] = row;
        ksoff[r] = (slot ^ (row & 7)) * 8;
        ksbase[r] = (w + 4 * r) * 1024;
    }
    // V staging: thread handles keys {cv,16+cv,32+cv,48+cv} -> pi-pos 4cv..4cv+3
    const int cv  = tid & 15;
    const int vd0 = (tid >> 4) << 2;

    const unsigned short* kbase = k + (size_t)(b * SEQ) * D_MODEL + h * DK;
    const unsigned short* vbase = v + (size_t)(b * SEQ) * D_MODEL + h * DK;

    us4 vrA, vrB, vrC, vrD;   // V in-flight registers

    auto issue_stage = [&](int kt, int buf) {
        const unsigned short* kp = kbase + (size_t)(kt * 64) * D_MODEL;
        #pragma unroll
        for (int r = 0; r < 2; ++r)
            gload_lds16(kp + (size_t)ksrow[r] * D_MODEL + ksoff[r],
                        (char*)lds_k + buf * 8192 + ksbase[r]);
        const unsigned short* vp = vbase + (size_t)(kt * 64 + cv) * D_MODEL + vd0;
        vrA = *(const us4*)(vp);
        vrB = *(const us4*)(vp + 16 * D_MODEL);
        vrC = *(const us4*)(vp + 32 * D_MODEL);
        vrD = *(const us4*)(vp + 48 * D_MODEL);
    };
    auto write_v = [&](int buf) {
        #pragma unroll
        for (int j = 0; j < 4; ++j) {
            uint2 pk;
            pk.x = (unsigned)vrA[j] | ((unsigned)vrB[j] << 16);
            pk.y = (unsigned)vrC[j] | ((unsigned)vrD[j] << 16);
            *(uint2*)((char*)lds_v + buf * 8192 + SW(vd0 + j, 8 * cv)) = pk;
        }
    };

    issue_stage(0, 0);
    write_v(0);
    __syncthreads();

    int cur = 0;
    for (int kt = 0; kt < SEQ / 64; ++kt) {
        const int nxt = cur ^ 1;
        const bool more = (kt + 1 < SEQ / 64);
        if (more) issue_stage(kt + 1, nxt);   // async: overlaps full tile compute

        // ---- S = Q @ K^T (exp2 domain; scale pre-folded into Q) ----
        f32x4 sacc[4] = {f32x4{0,0,0,0}, f32x4{0,0,0,0}, f32x4{0,0,0,0}, f32x4{0,0,0,0}};
        #pragma unroll
        for (int kstep = 0; kstep < 2; ++kstep) {
            short8 af = kstep ? qf1 : qf0;
            #pragma unroll
            for (int ks = 0; ks < 4; ++ks) {
                short8 bf = *(const short8*)((const char*)lds_k + cur * 8192 +
                             SW(ks * 16 + c, kstep * 64 + g * 16));
                sacc[ks] = __builtin_amdgcn_mfma_f32_16x16x32_bf16(af, bf, sacc[ks], 0, 0, 0);
            }
        }

        // ---- online softmax with defer-max (T13, THR=11 in log2 domain) ----
        float rm[4];
        #pragma unroll
        for (int reg = 0; reg < 4; ++reg)
            rm[reg] = fmaxf(fmaxf(sacc[0][reg], sacc[1][reg]),
                            fmaxf(sacc[2][reg], sacc[3][reg]));
        float cm = fmaxf(fmaxf(rm[0], rm[1]), fmaxf(rm[2], rm[3]));
        cm = fmaxf(cm, __shfl_xor(cm, 1));
        cm = fmaxf(cm, __shfl_xor(cm, 2));
        cm = fmaxf(cm, __shfl_xor(cm, 4));
        cm = fmaxf(cm, __shfl_xor(cm, 8));
        const float mmin = fminf(fminf(m_run[0], m_run[1]), fminf(m_run[2], m_run[3]));
        if (!__all(cm <= mmin + 11.0f)) {
            #pragma unroll
            for (int reg = 0; reg < 4; ++reg) {
                float mx = rm[reg];
                mx = fmaxf(mx, __shfl_xor(mx, 1));
                mx = fmaxf(mx, __shfl_xor(mx, 2));
                mx = fmaxf(mx, __shfl_xor(mx, 4));
                mx = fmaxf(mx, __shfl_xor(mx, 8));
                const float mnew = fmaxf(m_run[reg], mx);
                const float sc = fast_exp2(m_run[reg] - mnew);
                m_run[reg] = mnew;
                l_run[reg] *= sc;
                o[0][reg] *= sc;
                o[1][reg] *= sc;
                o[2][reg] *= sc;
                o[3][reg] *= sc;
            }
        }
        #pragma unroll
        for (int reg = 0; reg < 4; ++reg) {
            const float m = m_run[reg];
            float p0 = fast_exp2(sacc[0][reg] - m);
            float p1 = fast_exp2(sacc[1][reg] - m);
            float p2 = fast_exp2(sacc[2][reg] - m);
            float p3 = fast_exp2(sacc[3][reg] - m);
            float ps = (p0 + p1) + (p2 + p3);
            ps += __shfl_xor(ps, 1);
            ps += __shfl_xor(ps, 2);
            ps += __shfl_xor(ps, 4);
            ps += __shfl_xor(ps, 8);
            l_run[reg] += ps;
            uint2 pw;
            pw.x = f2bf2(p0, p1);   // pi-positions 4c, 4c+1
            pw.y = f2bf2(p2, p3);   // pi-positions 4c+2, 4c+3
            *(uint2*)((char*)lds_p[w] + SW((g << 2) + reg, 8 * c)) = pw;
        }

        // ---- O += P @ V (both sides in pi-key order) ----
        #pragma unroll
        for (int kstep = 0; kstep < 2; ++kstep) {
            short8 paf = *(const short8*)((const char*)lds_p[w] +
                          SW(c, kstep * 64 + g * 16));
            #pragma unroll
            for (int dsub = 0; dsub < 4; ++dsub) {
                short8 vbf = *(const short8*)((const char*)lds_v + cur * 8192 +
                              SW(dsub * 16 + c, kstep * 64 + g * 16));
                o[dsub] = __builtin_amdgcn_mfma_f32_16x16x32_bf16(paf, vbf, o[dsub], 0, 0, 0);
            }
        }

        if (more) {
            write_v(nxt);       // vmcnt wait lands here, after a full tile of compute
            __syncthreads();    // drains K staging; protects cur before overwrite
            cur = nxt;
        }
    }

    // ---- normalize, store ctx as bf16 ----
    #pragma unroll
    for (int reg = 0; reg < 4; ++reg) {
        const int qrow = q0 + (w << 4) + (g << 2) + reg;
        unsigned short* cb = ctx + (size_t)(b * SEQ + qrow) * D_MODEL + h * DK;
        const float invl = 1.f / l_run[reg];
        #pragma unroll
        for (int dsub = 0; dsub < 4; ++dsub)
            cb[dsub * 16 + c] = f2bf1(o[dsub][reg] * invl);
    }
}

// ---------------------------------------------------------------------------
extern "C" void kernel_launch(void* const* d_in, const int* in_sizes, int n_in,
                              void* d_out, int out_size, void* d_ws, size_t ws_size,
                              hipStream_t stream) {
    const float* query = (const float*)d_in[0];
    const float* key   = (const float*)d_in[1];
    const float* value = (const float*)d_in[2];
    const float* Wq = (const float*)d_in[3];
    const float* bq = (const float*)d_in[4];
    const float* Wk = (const float*)d_in[5];
    const float* bk = (const float*)d_in[6];
    const float* Wv = (const float*)d_in[7];
    const float* bv = (const float*)d_in[8];
    const float* Wo = (const float*)d_in[9];
    const float* bo = (const float*)d_in[10];
    float* out = (float*)d_out;

    const size_t mat = (size_t)MTOT * D_MODEL;      // 3.145M elems
    unsigned short* qx  = (unsigned short*)d_ws;    // bf16 inputs
    unsigned short* kx  = qx + mat;
    unsigned short* vx  = kx + mat;
    unsigned short* qb  = vx + mat;                 // projected Q/K/V (bf16)
    unsigned short* kb  = qb + mat;
    unsigned short* vb  = kb + mat;
    unsigned short* cb  = vb + mat;                 // context (bf16)
    unsigned short* Wqt = cb + mat;                 // transposed bf16 weights
    unsigned short* Wkt = Wqt + D_MODEL * D_MODEL;
    unsigned short* Wvt = Wkt + D_MODEL * D_MODEL;
    unsigned short* Wot = Wvt + D_MODEL * D_MODEL;

    const int n8 = (int)(mat / 8);
    cvt_in_k<<<dim3((n8 + 255) / 256, 3), 256, 0, stream>>>(
        query, key, value, qx, kx, vx, n8);
    cvt_wt_k<<<dim3(D_MODEL / 32, D_MODEL / 32, 4), 256, 0, stream>>>(
        Wq, Wk, Wv, Wo, Wqt, Wkt, Wvt, Wot);

    gemm_qkv_k<<<dim3(D_MODEL / 64, MTOT / 64, 3), 256, 0, stream>>>(
        qx, kx, vx, Wqt, Wkt, Wvt, bq, bk, bv, qb, kb, vb);

    attn_mfma_k<<<dim3(SEQ / 64, HEADS, BATCH), 256, 0, stream>>>(qb, kb, vb, cb);

    gemm_o_k<<<dim3(D_MODEL / 64, MTOT / 64), 256, 0, stream>>>(cb, Wot, bo, out);
}

// Round 5
// 136.270 us; speedup vs baseline: 5.6195x; 1.0250x over previous
//
#include <hip/hip_runtime.h>
#include <hip/hip_bf16.h>
#include <math.h>

#define D_MODEL 768
#define HEADS 12
#define DK 64
#define SEQ 2048
#define BATCH 2
#define MTOT (BATCH * SEQ)   // 4096
#define QSCALE 0.18033688011112042f   // 0.125 * log2(e): softmax in exp2 domain

using short8 = __attribute__((ext_vector_type(8))) short;
using us4    = __attribute__((ext_vector_type(4))) unsigned short;
using f32x4  = __attribute__((ext_vector_type(4))) float;

// ---------------- helpers ---------------------------------------------------
static __device__ __forceinline__ unsigned f2bf2(float x, float y) {
    __hip_bfloat162 t = __float22bfloat162_rn(float2{x, y});
    return *reinterpret_cast<unsigned*>(&t);
}
static __device__ __forceinline__ unsigned short f2bf1(float x) {
    __hip_bfloat16 t = __float2bfloat16(x);
    return *reinterpret_cast<unsigned short*>(&t);
}
static __device__ __forceinline__ float fast_exp2(float x) {
#if __has_builtin(__builtin_amdgcn_exp2f)
    return __builtin_amdgcn_exp2f(x);
#else
    return __expf(x * 0.6931471805599453f);
#endif
}

// XOR swizzle for 128-byte LDS rows: flips 16B slot by row&7
#define SW(row, byteoff) (((row) << 7) + ((byteoff) ^ (((row) & 7) << 4)))

// async global->LDS, 16B per lane; LDS dst wave-uniform base + lane*16
static __device__ __forceinline__ void gload_lds16(const void* g, void* l) {
    __builtin_amdgcn_global_load_lds(
        (const __attribute__((address_space(1))) void*)g,
        (__attribute__((address_space(3))) void*)l, 16, 0, 0);
}

// raw barrier with LDS-drain only (NO vmcnt drain -> prefetch stays in flight)
static __device__ __forceinline__ void barrier_lgkm() {
    asm volatile("s_waitcnt lgkmcnt(0)" ::: "memory");
    __builtin_amdgcn_s_barrier();
    __builtin_amdgcn_sched_barrier(0);
}
// raw barrier retiring all but the newest 4 VMEM ops (gload_lds prefetch-2)
static __device__ __forceinline__ void barrier_vm4() {
    asm volatile("s_waitcnt vmcnt(4)" ::: "memory");
    __builtin_amdgcn_s_barrier();
    __builtin_amdgcn_sched_barrier(0);
}

// ---------------- pre-pass: fp32 -> bf16 (q,k,v fused via blockIdx.y) -------
__global__ __launch_bounds__(256) void cvt_in_k(
    const float* __restrict__ q, const float* __restrict__ k, const float* __restrict__ v,
    unsigned short* __restrict__ qx, unsigned short* __restrict__ kx,
    unsigned short* __restrict__ vx, int n8)
{
    const int z = blockIdx.y;
    const float* x = z == 0 ? q : z == 1 ? k : v;
    unsigned short* y = z == 0 ? qx : z == 1 ? kx : vx;
    int i = blockIdx.x * 256 + threadIdx.x;
    if (i >= n8) return;
    const float4* xp = (const float4*)x;
    float4 a = xp[2 * i], b = xp[2 * i + 1];
    union { unsigned u[4]; short8 s; } r;
    r.u[0] = f2bf2(a.x, a.y);
    r.u[1] = f2bf2(a.z, a.w);
    r.u[2] = f2bf2(b.x, b.y);
    r.u[3] = f2bf2(b.z, b.w);
    ((short8*)y)[i] = r.s;
}

// ---------------- pre-pass: W[k][n] fp32 -> Wt[n][k] bf16 (4 W's fused) -----
__global__ __launch_bounds__(256) void cvt_wt_k(
    const float* __restrict__ Wq, const float* __restrict__ Wk,
    const float* __restrict__ Wv, const float* __restrict__ Wo,
    unsigned short* __restrict__ Wqt, unsigned short* __restrict__ Wkt,
    unsigned short* __restrict__ Wvt, unsigned short* __restrict__ Wot)
{
    const int z = blockIdx.z;
    const float* W = z == 0 ? Wq : z == 1 ? Wk : z == 2 ? Wv : Wo;
    unsigned short* Wt = z == 0 ? Wqt : z == 1 ? Wkt : z == 2 ? Wvt : Wot;
    __shared__ float t[32][33];
    const int n0 = blockIdx.x * 32, k0 = blockIdx.y * 32;
    const int tx = threadIdx.x & 31;
    const int ty0 = (threadIdx.x >> 5) * 4;
    #pragma unroll
    for (int j = 0; j < 4; ++j)
        t[ty0 + j][tx] = W[(size_t)(k0 + ty0 + j) * D_MODEL + n0 + tx];
    __syncthreads();
    #pragma unroll
    for (int j = 0; j < 4; ++j)
        Wt[(size_t)(n0 + ty0 + j) * D_MODEL + k0 + tx] = f2bf1(t[tx][ty0 + j]);
}

// ---------------- bf16 MFMA GEMM: 64x64 tile, BK=64, prefetch-2 (3 bufs) ----
template <int OUT_BF16>
static __device__ __forceinline__ void gemm_body(
    const unsigned short* __restrict__ A, const unsigned short* __restrict__ Wt,
    const float* __restrict__ bias, void* __restrict__ C, float scale)
{
    __shared__ unsigned short As[3][64 * 64];   // 8 KB each
    __shared__ unsigned short Bs[3][64 * 64];

    const int tid  = threadIdx.x;
    const int w    = tid >> 6;
    const int lane = tid & 63;
    const int g    = lane >> 4, c = lane & 15;
    const int wr   = w >> 1, wc = w & 1;
    const int brow = blockIdx.y * 64;
    const int bcol = blockIdx.x * 64;

    f32x4 acc[2][2] = {{f32x4{0,0,0,0}, f32x4{0,0,0,0}},
                       {f32x4{0,0,0,0}, f32x4{0,0,0,0}}};

    int srow[2], soff[2], sbase[2];
    #pragma unroll
    for (int r = 0; r < 2; ++r) {
        int phys = (w + 4 * r) * 1024 + lane * 16;
        int row  = phys >> 7;
        int slot = (phys >> 4) & 7;
        srow[r]  = row;
        soff[r]  = (slot ^ (row & 7)) * 8;
        sbase[r] = (w + 4 * r) * 1024;
    }

    auto stage = [&](int k0, int buf) {
        #pragma unroll
        for (int r = 0; r < 2; ++r) {
            gload_lds16(A  + (size_t)(brow + srow[r]) * D_MODEL + k0 + soff[r],
                        (char*)As + buf * 8192 + sbase[r]);
            gload_lds16(Wt + (size_t)(bcol + srow[r]) * D_MODEL + k0 + soff[r],
                        (char*)Bs + buf * 8192 + sbase[r]);
        }
    };

    // prologue: tiles 0,1 in flight (8 ops); retire tile 0 (oldest 4)
    stage(0, 0);
    stage(64, 1);
    barrier_vm4();

    int cur3 = 0, pf3 = 2;
    for (int k0 = 0; k0 < D_MODEL; k0 += 64) {
        // unconditional clamped prefetch keeps vmcnt statically countable:
        // steady state = 8 outstanding; barrier_vm4 retires oldest 4 = tile k0+64.
        const int kpf = min(k0 + 128, D_MODEL - 64);
        stage(kpf, pf3);

        #pragma unroll
        for (int kstep = 0; kstep < 2; ++kstep) {
            short8 af[2], bf[2];
            #pragma unroll
            for (int m = 0; m < 2; ++m)
                af[m] = *(const short8*)((const char*)As + cur3 * 8192 +
                         SW(wr * 32 + m * 16 + c, kstep * 64 + g * 16));
            #pragma unroll
            for (int n = 0; n < 2; ++n)
                bf[n] = *(const short8*)((const char*)Bs + cur3 * 8192 +
                         SW(wc * 32 + n * 16 + c, kstep * 64 + g * 16));
            #pragma unroll
            for (int m = 0; m < 2; ++m)
                #pragma unroll
                for (int n = 0; n < 2; ++n)
                    acc[m][n] = __builtin_amdgcn_mfma_f32_16x16x32_bf16(
                                    af[m], bf[n], acc[m][n], 0, 0, 0);
        }
        barrier_vm4();
        cur3 = cur3 == 2 ? 0 : cur3 + 1;
        pf3  = pf3  == 2 ? 0 : pf3 + 1;
    }

    #pragma unroll
    for (int m = 0; m < 2; ++m)
        #pragma unroll
        for (int n = 0; n < 2; ++n) {
            const int col = bcol + wc * 32 + n * 16 + c;
            const float bval = bias[col];
            #pragma unroll
            for (int j = 0; j < 4; ++j) {
                const int row = brow + wr * 32 + m * 16 + g * 4 + j;
                const float val = (acc[m][n][j] + bval) * scale;
                if (OUT_BF16)
                    ((unsigned short*)C)[(size_t)row * D_MODEL + col] = f2bf1(val);
                else
                    ((float*)C)[(size_t)row * D_MODEL + col] = val;
            }
        }
}

__global__ __launch_bounds__(256) void gemm_qkv_k(
    const unsigned short* __restrict__ qx, const unsigned short* __restrict__ kx,
    const unsigned short* __restrict__ vx,
    const unsigned short* __restrict__ Wqt, const unsigned short* __restrict__ Wkt,
    const unsigned short* __restrict__ Wvt,
    const float* __restrict__ bq, const float* __restrict__ bk,
    const float* __restrict__ bv,
    unsigned short* __restrict__ qb, unsigned short* __restrict__ kb,
    unsigned short* __restrict__ vb)
{
    const int z = blockIdx.z;
    const unsigned short* A  = z == 0 ? qx  : z == 1 ? kx  : vx;
    const unsigned short* Wt = z == 0 ? Wqt : z == 1 ? Wkt : Wvt;
    const float* bias        = z == 0 ? bq  : z == 1 ? bk  : bv;
    unsigned short* C        = z == 0 ? qb  : z == 1 ? kb  : vb;
    gemm_body<1>(A, Wt, bias, C, z == 0 ? QSCALE : 1.0f);
}

__global__ __launch_bounds__(256) void gemm_o_k(
    const unsigned short* __restrict__ A, const unsigned short* __restrict__ Wt,
    const float* __restrict__ bias, float* __restrict__ C)
{
    gemm_body<0>(A, Wt, bias, C, 1.0f);
}

// ---------------- Flash attention: prefetch-2, counted waits, l via MFMA ----
// grid 768 (flat, XCD-chunk swizzled), 256 thr = 4 waves; wave w: q-rows [16w,16w+16)
// K: 3 LDS buffers (gload_lds). V: 2 named reg sets + 2 LDS buffers.
// Per-tile VMEM issue order: K(2 ops), V(4 ops). write_vr's reg-dep makes the
// compiler emit vmcnt(6) (retires K/V of tile kt+1; tile kt+2 stays in flight).
struct VR { us4 a, b, c, d; };

__global__ __launch_bounds__(256) void attn_mfma_k(
    const unsigned short* __restrict__ q, const unsigned short* __restrict__ k,
    const unsigned short* __restrict__ v, unsigned short* __restrict__ ctx)
{
    __shared__ unsigned short lds_k[3][64 * 64];   // [key][d] swizzled
    __shared__ unsigned short lds_v[2][64 * 64];   // [d][pi(key)] swizzled
    __shared__ unsigned short lds_p[4][16 * 64];   // per-wave [row][pi(key)]

    const int tid  = threadIdx.x;
    const int w    = tid >> 6;
    const int lane = tid & 63;
    const int g    = lane >> 4;
    const int c    = lane & 15;

    // XCD-chunk swizzle: each XCD gets 96 consecutive logical blocks = 3 (b,h)
    // groups -> K/V panels L2-resident per XCD.
    const int bid = blockIdx.x;
    const int swz = (bid & 7) * 96 + (bid >> 3);
    const int qt  = swz & 31;
    const int hb  = swz >> 5;
    const int h   = hb % HEADS;
    const int b   = hb / HEADS;
    const int q0  = qt * 64;
    const int NT  = SEQ / 64;   // 32 (even -> clean unroll-by-2)

    // Q strip A-frags (pre-scaled by QSCALE in the projection GEMM)
    short8 qf0, qf1;
    {
        const int qrow = q0 + (w << 4) + c;
        const unsigned short* qp = q + (size_t)(b * SEQ + qrow) * D_MODEL + h * DK;
        qf0 = *(const short8*)(qp + g * 8);
        qf1 = *(const short8*)(qp + 32 + g * 8);
    }

    float m_run[4] = {-INFINITY, -INFINITY, -INFINITY, -INFINITY};
    f32x4 lacc = f32x4{0, 0, 0, 0};    // l[4g+reg], accumulated by MFMA vs ones
    f32x4 o[4] = {f32x4{0,0,0,0}, f32x4{0,0,0,0}, f32x4{0,0,0,0}, f32x4{0,0,0,0}};

    const short8 ONES = {0x3F80, 0x3F80, 0x3F80, 0x3F80,
                         0x3F80, 0x3F80, 0x3F80, 0x3F80};   // bf16 1.0 x8

    // K staging geometry (pre-swizzled source, linear LDS dest)
    int ksrow[2], ksoff[2], ksbase[2];
    #pragma unroll
    for (int r = 0; r < 2; ++r) {
        int phys = (w + 4 * r) * 1024 + lane * 16;
        int row  = phys >> 7;
        int slot = (phys >> 4) & 7;
        ksrow[r] = row;
        ksoff[r] = (slot ^ (row & 7)) * 8;
        ksbase[r] = (w + 4 * r) * 1024;
    }
    // V staging: thread handles keys {cv,16+cv,32+cv,48+cv} -> pi-pos 4cv..4cv+3
    const int cv  = tid & 15;
    const int vd0 = (tid >> 4) << 2;

    const unsigned short* kbase = k + (size_t)(b * SEQ) * D_MODEL + h * DK;
    const unsigned short* vbase = v + (size_t)(b * SEQ) * D_MODEL + h * DK;

    auto issue_k = [&](int tile, int buf) {
        const unsigned short* kp = kbase + (size_t)(tile * 64) * D_MODEL;
        #pragma unroll
        for (int r = 0; r < 2; ++r)
            gload_lds16(kp + (size_t)ksrow[r] * D_MODEL + ksoff[r],
                        (char*)lds_k + buf * 8192 + ksbase[r]);
    };
    auto load_vr = [&](int tile, VR& r) {
        const unsigned short* vp = vbase + (size_t)(tile * 64 + cv) * D_MODEL + vd0;
        r.a = *(const us4*)(vp);
        r.b = *(const us4*)(vp + 16 * D_MODEL);
        r.c = *(const us4*)(vp + 32 * D_MODEL);
        r.d = *(const us4*)(vp + 48 * D_MODEL);
    };
    auto write_vr = [&](VR& r, int buf) {
        #pragma unroll
        for (int j = 0; j < 4; ++j) {
            uint2 pk;
            pk.x = (unsigned)r.a[j] | ((unsigned)r.b[j] << 16);
            pk.y = (unsigned)r.c[j] | ((unsigned)r.d[j] << 16);
            *(uint2*)((char*)lds_v + buf * 8192 + SW(vd0 + j, 8 * cv)) = pk;
        }
    };

    auto tile_body = [&](int kt, int cur3, int pf3, VR& vcur, VR& vnxt) {
        // prefetch tile kt+2 (clamped dup at tail keeps vmcnt statically countable)
        const int pft = min(kt + 2, NT - 1);
        issue_k(pft, pf3);
        load_vr(pft, vcur);
        __builtin_amdgcn_sched_barrier(0);   // pin issue position (no sinking)

        // ---- S = Q @ K^T (exp2 domain) ----
        f32x4 sacc[4] = {f32x4{0,0,0,0}, f32x4{0,0,0,0}, f32x4{0,0,0,0}, f32x4{0,0,0,0}};
        #pragma unroll
        for (int kstep = 0; kstep < 2; ++kstep) {
            short8 af = kstep ? qf1 : qf0;
            #pragma unroll
            for (int ks = 0; ks < 4; ++ks) {
                short8 bf = *(const short8*)((const char*)lds_k + cur3 * 8192 +
                             SW(ks * 16 + c, kstep * 64 + g * 16));
                sacc[ks] = __builtin_amdgcn_mfma_f32_16x16x32_bf16(af, bf, sacc[ks], 0, 0, 0);
            }
        }

        // ---- defer-max online softmax ----
        float rm[4];
        #pragma unroll
        for (int reg = 0; reg < 4; ++reg)
            rm[reg] = fmaxf(fmaxf(sacc[0][reg], sacc[1][reg]),
                            fmaxf(sacc[2][reg], sacc[3][reg]));
        float cm = fmaxf(fmaxf(rm[0], rm[1]), fmaxf(rm[2], rm[3]));
        cm = fmaxf(cm, __shfl_xor(cm, 1));
        cm = fmaxf(cm, __shfl_xor(cm, 2));
        cm = fmaxf(cm, __shfl_xor(cm, 4));
        cm = fmaxf(cm, __shfl_xor(cm, 8));
        const float mmin = fminf(fminf(m_run[0], m_run[1]), fminf(m_run[2], m_run[3]));
        if (!__all(cm <= mmin + 11.0f)) {
            #pragma unroll
            for (int reg = 0; reg < 4; ++reg) {
                float mx = rm[reg];
                mx = fmaxf(mx, __shfl_xor(mx, 1));
                mx = fmaxf(mx, __shfl_xor(mx, 2));
                mx = fmaxf(mx, __shfl_xor(mx, 4));
                mx = fmaxf(mx, __shfl_xor(mx, 8));
                const float mnew = fmaxf(m_run[reg], mx);
                const float sc = fast_exp2(m_run[reg] - mnew);
                m_run[reg] = mnew;
                lacc[reg] *= sc;
                o[0][reg] *= sc;
                o[1][reg] *= sc;
                o[2][reg] *= sc;
                o[3][reg] *= sc;
            }
        }
        #pragma unroll
        for (int reg = 0; reg < 4; ++reg) {
            const float m = m_run[reg];
            float p0 = fast_exp2(sacc[0][reg] - m);
            float p1 = fast_exp2(sacc[1][reg] - m);
            float p2 = fast_exp2(sacc[2][reg] - m);
            float p3 = fast_exp2(sacc[3][reg] - m);
            uint2 pw;
            pw.x = f2bf2(p0, p1);   // pi-positions 4c, 4c+1
            pw.y = f2bf2(p2, p3);   // pi-positions 4c+2, 4c+3
            *(uint2*)((char*)lds_p[w] + SW((g << 2) + reg, 8 * c)) = pw;
        }

        // ---- O += P @ V ; l += P @ ones (2 MFMAs replace shuffle-sum) ----
        const int curv = kt & 1;
        #pragma unroll
        for (int kstep = 0; kstep < 2; ++kstep) {
            short8 paf = *(const short8*)((const char*)lds_p[w] +
                          SW(c, kstep * 64 + g * 16));
            lacc = __builtin_amdgcn_mfma_f32_16x16x32_bf16(paf, ONES, lacc, 0, 0, 0);
            #pragma unroll
            for (int dsub = 0; dsub < 4; ++dsub) {
                short8 vbf = *(const short8*)((const char*)lds_v + curv * 8192 +
                              SW(dsub * 16 + c, kstep * 64 + g * 16));
                o[dsub] = __builtin_amdgcn_mfma_f32_16x16x32_bf16(paf, vbf, o[dsub], 0, 0, 0);
            }
        }

        // V(kt+1) regs -> LDS (reg-dep forces counted vmcnt, keeps prefetch alive)
        write_vr(vnxt, curv ^ 1);
        barrier_lgkm();
    };

    // prologue: tiles 0,1 in flight; V(0) to LDS; K(0) retired via V(0)'s reg-dep
    VR vr0, vr1;
    issue_k(0, 0);
    load_vr(0, vr0);
    issue_k(1, 1);
    load_vr(1, vr1);
    write_vr(vr0, 0);
    barrier_lgkm();

    int cur3 = 0;
    for (int kt = 0; kt < NT; kt += 2) {
        tile_body(kt,     cur3,             (cur3 + 2) % 3, vr0, vr1);
        tile_body(kt + 1, (cur3 + 1) % 3,   cur3,           vr1, vr0);
        cur3 = (cur3 + 2) % 3;
    }

    // ---- normalize, store ctx as bf16 ----
    #pragma unroll
    for (int reg = 0; reg < 4; ++reg) {
        const int qrow = q0 + (w << 4) + (g << 2) + reg;
        unsigned short* cb = ctx + (size_t)(b * SEQ + qrow) * D_MODEL + h * DK;
        const float invl = 1.f / lacc[reg];
        #pragma unroll
        for (int dsub = 0; dsub < 4; ++dsub)
            cb[dsub * 16 + c] = f2bf1(o[dsub][reg] * invl);
    }
}

// ---------------------------------------------------------------------------
extern "C" void kernel_launch(void* const* d_in, const int* in_sizes, int n_in,
                              void* d_out, int out_size, void* d_ws, size_t ws_size,
                              hipStream_t stream) {
    const float* query = (const float*)d_in[0];
    const float* key   = (const float*)d_in[1];
    const float* value = (const float*)d_in[2];
    const float* Wq = (const float*)d_in[3];
    const float* bq = (const float*)d_in[4];
    const float* Wk = (const float*)d_in[5];
    const float* bk = (const float*)d_in[6];
    const float* Wv = (const float*)d_in[7];
    const float* bv = (const float*)d_in[8];
    const float* Wo = (const float*)d_in[9];
    const float* bo = (const float*)d_in[10];
    float* out = (float*)d_out;

    const size_t mat = (size_t)MTOT * D_MODEL;      // 3.145M elems
    unsigned short* qx  = (unsigned short*)d_ws;    // bf16 inputs
    unsigned short* kx  = qx + mat;
    unsigned short* vx  = kx + mat;
    unsigned short* qb  = vx + mat;                 // projected Q/K/V (bf16)
    unsigned short* kb  = qb + mat;
    unsigned short* vb  = kb + mat;
    unsigned short* cb  = vb + mat;                 // context (bf16)
    unsigned short* Wqt = cb + mat;                 // transposed bf16 weights
    unsigned short* Wkt = Wqt + D_MODEL * D_MODEL;
    unsigned short* Wvt = Wkt + D_MODEL * D_MODEL;
    unsigned short* Wot = Wvt + D_MODEL * D_MODEL;

    const int n8 = (int)(mat / 8);
    cvt_in_k<<<dim3((n8 + 255) / 256, 3), 256, 0, stream>>>(
        query, key, value, qx, kx, vx, n8);
    cvt_wt_k<<<dim3(D_MODEL / 32, D_MODEL / 32, 4), 256, 0, stream>>>(
        Wq, Wk, Wv, Wo, Wqt, Wkt, Wvt, Wot);

    gemm_qkv_k<<<dim3(D_MODEL / 64, MTOT / 64, 3), 256, 0, stream>>>(
        qx, kx, vx, Wqt, Wkt, Wvt, bq, bk, bv, qb, kb, vb);

    attn_mfma_k<<<dim3(SEQ / 64 * HEADS * BATCH), 256, 0, stream>>>(qb, kb, vb, cb);

    gemm_o_k<<<dim3(D_MODEL / 64, MTOT / 64), 256, 0, stream>>>(cb, Wot, bo, out);
}